// Round 12
// baseline (72.602 us; speedup 1.0000x reference)
//
#include <hip/hip_runtime.h>
#include <math.h>

#define MD 128
#define NA 2048
#define AS 512
#define NS 32768
#define NBE 512
#define W1 768
#define W2 1280
#define PI 3.14159265358979323846
#define KTH ((float)(PI / 98304.0))

__device__ __forceinline__ float lrelu(float v) { return v > 0.f ? v : 0.2f * v; }

// ---------------------------------------------------------------------------
// P8 far evaluation for one (t, e): Taylor of cot around atom center, masked
// to 0 inside the near window. (Round-8-proven formula.)
// ---------------------------------------------------------------------------
__device__ __forceinline__ float p8_far(float tf, float4 A, float4 B, float4 C)
{
  float u  = tf - A.x;
  float th = u * KTH;
  float sn = __sinf(th);
  float cs = __cosf(th);
  float c  = cs * __builtin_amdgcn_rcpf(sn);
  float u2  = __builtin_fmaf(c, c, 1.f);     // -a1
  float c2  = c + c;
  float u22 = u2 + u2;
  float a2  = c * u2;
  float a3  = (-1.f / 3.f) * __builtin_fmaf(c2, a2, u2 * u2);
  float a4  = 0.5f * __builtin_fmaf(-c, a3, u2 * a2);
  float s5  = __builtin_fmaf(c2, a4, a2 * a2);
  s5        = __builtin_fmaf(-u22, a3, s5);
  float a5  = -0.2f * s5;
  float s6  = __builtin_fmaf(c, a5, a2 * a3);
  s6        = __builtin_fmaf(-u2, a4, s6);
  float a6  = (-1.f / 3.f) * s6;
  float s7  = __builtin_fmaf(c2, a6, a3 * a3);
  s7        = __builtin_fmaf(-u22, a5, s7);
  s7        = __builtin_fmaf(2.f * a2, a4, s7);
  float a7  = (-1.f / 7.f) * s7;
  float s8  = __builtin_fmaf(c, a7, a3 * a4);
  s8        = __builtin_fmaf(-u2, a6, s8);
  s8        = __builtin_fmaf(a2, a5, s8);
  float a8  = -0.25f * s8;
  float y = c * A.w;
  y = __builtin_fmaf(-u2, B.x, y);
  y = __builtin_fmaf(a2, B.y, y);
  y = __builtin_fmaf(a3, B.z, y);
  y = __builtin_fmaf(a4, B.w, y);
  y = __builtin_fmaf(a5, C.x, y);
  y = __builtin_fmaf(a6, C.y, y);
  y = __builtin_fmaf(a7, C.z, y);
  y = __builtin_fmaf(a8, C.w, y);
  bool farq = (tf < A.y) || (tf >= A.z);
  return farq ? y : 0.f;
}

// ---------------------------------------------------------------------------
// prepA: single kernel, block-partitioned, no internal dependencies.
//   blocks [0,2048):    logits path. ot = bid&15, beg = bid>>4. Recomputes
//                       sel-hidden for its 4 be's inline (round-5 code),
//                       then logits + gumbel + shuffle argmax partials.
//   blocks [2048,2176): time stack fp64 (round-5 code), rg = bid-2048.
//   blocks [2176,2304): amp stack (round-5 code), rg = bid-2176.
// d_out zeroing spread over the first 512 blocks (gtid < 65536 float4s).
// ---------------------------------------------------------------------------
__global__ __launch_bounds__(128) void prepA_kernel(
    const float* __restrict__ x, const float* __restrict__ times,
    const float* __restrict__ gu,
    const float* __restrict__ tw0, const float* __restrict__ tb0,
    const float* __restrict__ tw1, const float* __restrict__ tb1,
    const float* __restrict__ tw2, const float* __restrict__ tb2,
    const float* __restrict__ sw0, const float* __restrict__ sb0,
    const float* __restrict__ sw1, const float* __restrict__ sb1,
    const float* __restrict__ sw2, const float* __restrict__ sb2,
    const float* __restrict__ aw0, const float* __restrict__ ab0,
    const float* __restrict__ aw1, const float* __restrict__ ab1,
    const float* __restrict__ aw2, const float* __restrict__ ab2,
    float* __restrict__ timev, float* __restrict__ ampv,
    float2* __restrict__ partials, float* __restrict__ out)
{
  const int bid = blockIdx.x;
  const int tid = threadIdx.x;

  // ---- zero d_out (replaces hipMemsetAsync dispatch) ----
  {
    const int gtid = bid * 128 + tid;
    if (gtid < (8 * NS) / 4) {
      ((float4*)out)[gtid] = make_float4(0.f, 0.f, 0.f, 0.f);
    }
  }

  __shared__ float xs[4][MD];
  __shared__ float fA[4][MD], fB[4][MD];

  if (bid < 2048) {
    // ================= logits path (with inline sel-hidden) =================
    const int ot  = bid & 15;
    const int beg = bid >> 4;
    const int o = ot * 128 + tid;
    const int wave = tid >> 6, lane = tid & 63;
    __shared__ float wv[2][4];
    __shared__ int wi[2][4];

#pragma unroll
    for (int j = 0; j < 4; ++j) xs[j][tid] = x[(beg * 4 + j) * MD + tid];
    __syncthreads();

    // sel-hidden layer 0
    {
      float b = sb0[tid];
      float s[4] = {b, b, b, b};
#pragma unroll 8
      for (int k = 0; k < MD; ++k) {
        float w = sw0[k * MD + tid];
#pragma unroll
        for (int j = 0; j < 4; ++j) s[j] += xs[j][k] * w;
      }
#pragma unroll
      for (int j = 0; j < 4; ++j) fA[j][tid] = lrelu(s[j]);
      __syncthreads();
    }
    // sel-hidden layer 1
    {
      float b = sb1[tid];
      float s[4] = {b, b, b, b};
#pragma unroll 8
      for (int k = 0; k < MD; ++k) {
        float w = sw1[k * MD + tid];
#pragma unroll
        for (int j = 0; j < 4; ++j) s[j] += fA[j][k] * w;
      }
#pragma unroll
      for (int j = 0; j < 4; ++j) fB[j][tid] = lrelu(s[j]);
      __syncthreads();
    }

    // logits + gumbel + argmax partials (round-5 proven)
    float b = sb2[o];
    float acc[4] = {b, b, b, b};
#pragma unroll 16
    for (int k = 0; k < MD; ++k) {
      float w = sw2[k * NA + o];
#pragma unroll
      for (int j = 0; j < 4; ++j) acc[j] = fmaf(fB[j][k], w, acc[j]);
    }

#pragma unroll
    for (int j = 0; j < 4; ++j) {
      float u = gu[(beg * 4 + j) * NA + o];
      float g = -logf(-logf(u + 1e-10f) + 1e-10f);
      float v = acc[j] + g;
      int idx = o;
      for (int off = 32; off > 0; off >>= 1) {
        float ov = __shfl_xor(v, off);
        int oi = __shfl_xor(idx, off);
        if (ov > v || (ov == v && oi < idx)) { v = ov; idx = oi; }
      }
      if (lane == 0) { wv[wave][j] = v; wi[wave][j] = idx; }
    }
    __syncthreads();
    if (tid == 0) {
#pragma unroll
      for (int j = 0; j < 4; ++j) {
        float v0 = wv[0][j], v1 = wv[1][j];
        int i0 = wi[0][j], i1 = wi[1][j];
        bool take1 = (v1 > v0) || (v1 == v0 && i1 < i0);
        float bv = take1 ? v1 : v0;
        int bi = take1 ? i1 : i0;
        partials[(beg * 4 + j) * 16 + ot] = make_float2(bv, __int_as_float(bi));
      }
    }
    return;
  }

  // ================= time / amp paths =================
  __shared__ double dA[4][MD], dB[4][MD];
  const int stack = (bid < 2176) ? 0 : 1;
  const int rg = bid - (stack == 0 ? 2048 : 2176);

#pragma unroll
  for (int j = 0; j < 4; ++j) xs[j][tid] = x[(rg * 4 + j) * MD + tid];
  __syncthreads();

  if (stack == 0) {
    // ---- time stack, fp64 (dNc = 32767*dtime: precision-critical) ----
    {
      double b = (double)tb0[tid];
      double s[4] = {b, b, b, b};
#pragma unroll 8
      for (int k = 0; k < MD; ++k) {
        double w = (double)tw0[k * MD + tid];
#pragma unroll
        for (int j = 0; j < 4; ++j) s[j] += (double)xs[j][k] * w;
      }
#pragma unroll
      for (int j = 0; j < 4; ++j) dA[j][tid] = s[j] > 0.0 ? s[j] : 0.2 * s[j];
      __syncthreads();
    }
    {
      double b = (double)tb1[tid];
      double s[4] = {b, b, b, b};
#pragma unroll 8
      for (int k = 0; k < MD; ++k) {
        double w = (double)tw1[k * MD + tid];
#pragma unroll
        for (int j = 0; j < 4; ++j) s[j] += dA[j][k] * w;
      }
#pragma unroll
      for (int j = 0; j < 4; ++j) dB[j][tid] = s[j] > 0.0 ? s[j] : 0.2 * s[j];
      __syncthreads();
    }
    {
      double w2 = (double)tw2[tid];
#pragma unroll
      for (int j = 0; j < 4; ++j) dA[j][tid] = dB[j][tid] * w2;
      __syncthreads();
      for (int off = 64; off > 0; off >>= 1) {
        if (tid < off) {
#pragma unroll
          for (int j = 0; j < 4; ++j) dA[j][tid] += dA[j][tid + off];
        }
        __syncthreads();
      }
      if (tid == 0) {
#pragma unroll
        for (int j = 0; j < 4; ++j) {
          double tval = dA[j][0] + (double)tb2[0];
          double sg = 1.0 / (1.0 + exp(-tval));
          float tf = (float)sg;            // round like the fp32 reference
          timev[rg * 4 + j] = tf * 1.0f + times[rg * 4 + j];
        }
      }
    }
  } else {
    // ---- amp stack, fp32 ----
    {
      float b = ab0[tid];
      float s[4] = {b, b, b, b};
#pragma unroll 8
      for (int k = 0; k < MD; ++k) {
        float w = aw0[k * MD + tid];
#pragma unroll
        for (int j = 0; j < 4; ++j) s[j] += xs[j][k] * w;
      }
#pragma unroll
      for (int j = 0; j < 4; ++j) fA[j][tid] = lrelu(s[j]);
      __syncthreads();
    }
    {
      float b = ab1[tid];
      float s[4] = {b, b, b, b};
#pragma unroll 8
      for (int k = 0; k < MD; ++k) {
        float w = aw1[k * MD + tid];
#pragma unroll
        for (int j = 0; j < 4; ++j) s[j] += fA[j][k] * w;
      }
#pragma unroll
      for (int j = 0; j < 4; ++j) fB[j][tid] = lrelu(s[j]);
      __syncthreads();
    }
    {
      float w2 = aw2[tid];
#pragma unroll
      for (int j = 0; j < 4; ++j) fA[j][tid] = fB[j][tid] * w2;
      __syncthreads();
      for (int off = 64; off > 0; off >>= 1) {
        if (tid < off) {
#pragma unroll
          for (int j = 0; j < 4; ++j) fA[j][tid] += fA[j][tid + off];
        }
        __syncthreads();
      }
      if (tid == 0) {
#pragma unroll
        for (int j = 0; j < 4; ++j) {
          float av = fA[j][0] + ab2[0];
          ampv[rg * 4 + j] = av * av;
        }
      }
    }
  }
}

// ---------------------------------------------------------------------------
// finalize (round-11 proven): partials argmax + atom norm + shift params +
// G + moments M0..M12, atom row as one float4 read.
// ---------------------------------------------------------------------------
__global__ __launch_bounds__(128) void finalize_kernel(
    const float2* __restrict__ partials, const float* __restrict__ timev,
    const float* __restrict__ ampv, const float* __restrict__ atoms,
    float* __restrict__ G, int* __restrict__ m0s, float* __restrict__ fracs,
    float4* __restrict__ params, float4* __restrict__ mom2)
{
  const int be = blockIdx.x;
  const int tid = threadIdx.x;
  __shared__ float red[128];
  __shared__ float m_red[128][13];
  __shared__ float sc_coef, sc_inv;
  __shared__ int sc_idx;

  if (tid < 64) {
    float v = -3.4e38f;
    int idx = 0x7fffffff;
    if (tid < 16) {
      float2 p = partials[be * 16 + tid];
      v = p.x;
      idx = __float_as_int(p.y);
    }
    for (int off = 8; off > 0; off >>= 1) {
      float ov = __shfl_xor(v, off);
      int oi = __shfl_xor(idx, off);
      if (ov > v || (ov == v && oi < idx)) { v = ov; idx = oi; }
    }
    if (tid == 0) sc_idx = idx;
  }
  __syncthreads();
  const int idx = sc_idx;

  const float4 a4 = ((const float4*)(atoms + (size_t)idx * AS))[tid];

  {
    float ss = a4.x * a4.x + a4.y * a4.y + a4.z * a4.z + a4.w * a4.w;
    red[tid] = ss;
    __syncthreads();
    for (int off = 64; off > 0; off >>= 1) {
      if (tid < off) red[tid] += red[tid + off];
      __syncthreads();
    }
    if (tid == 0) {
      sc_inv = 1.f / (sqrtf(red[0]) + 1e-8f);
      double Nc = (double)timev[be] * (1610612736.0 / 49153.0);
      double rr = rint(Nc);
      int m0 = (int)rr;
      float fr = (float)(Nc - rr);
      if (fabsf(fr) < 1e-9f) fr = (fr < 0.f) ? -1e-9f : 1e-9f;
      m0s[be] = m0;
      fracs[be] = fr;
      sc_coef = ampv[be] * ((m0 & 1) ? 1.0f : -1.0f) *
                sinf((float)PI * fr) * (1.0f / 98304.0f);
      red[64] = (float)m0;
      red[65] = fr;
    }
    __syncthreads();
  }

  const float cf = sc_coef * sc_inv;
  float mk[13];
#pragma unroll
  for (int k = 0; k < 13; ++k) mk[k] = 0.f;
  const float av4[4] = {a4.x * cf, a4.y * cf, a4.z * cf, a4.w * cf};
  float4 gv4;
  float* gvp = (float*)&gv4;
  const int t0 = tid * 4;
#pragma unroll
  for (int j = 0; j < 4; ++j) {
    const int t = t0 + j;
    float gv = (j & 1) ? -av4[j] : av4[j];   // t0 even -> parity = j parity
    gvp[j] = gv;
    float q = (255.5f - (float)t) * KTH;     // -(tau-255.5)*pi/N
    float pw = gv;
    mk[0] += pw;
#pragma unroll
    for (int k = 1; k < 13; ++k) { pw *= q; mk[k] += pw; }
  }
  ((float4*)(G + (size_t)be * AS))[tid] = gv4;
#pragma unroll
  for (int k = 0; k < 13; ++k) m_red[tid][k] = mk[k];
  __syncthreads();
  for (int off = 64; off > 0; off >>= 1) {
    if (tid < off) {
#pragma unroll
      for (int k = 0; k < 13; ++k) m_red[tid][k] += m_red[tid + off][k];
    }
    __syncthreads();
  }
  if (tid == 0) {
    int m0 = (int)red[64];
    float fr = red[65];
    float uc = (float)((double)m0 + (double)fr + 255.5);
    params[be * 3 + 0] = make_float4(uc, (float)(m0 - W1), (float)(m0 + W2), m_red[0][0]);
    params[be * 3 + 1] = make_float4(m_red[0][1], m_red[0][2], m_red[0][3], m_red[0][4]);
    params[be * 3 + 2] = make_float4(m_red[0][5], m_red[0][6], m_red[0][7], m_red[0][8]);
    mom2[be] = make_float4(m_red[0][9], m_red[0][10], m_red[0][11], m_red[0][12]);
  }
}

// ---------------------------------------------------------------------------
// field (round-11 proven): blocks [0,512) = near conv (split-table);
// blocks [512,1536) = far: inline per-tile coeff collapse then Horner.
// ---------------------------------------------------------------------------
__global__ __launch_bounds__(256) void field_kernel(
    const float4* __restrict__ params, const float4* __restrict__ mom2,
    const float* __restrict__ G, const int* __restrict__ m0s,
    const float* __restrict__ fracs, float* __restrict__ out)
{
  __shared__ float4 SMEM[768];   // near: Tsplit[640]+Gl4[128] | far: coeff area
  const int bid = blockIdx.x;
  const int tid = threadIdx.x;

  if (bid >= 512) {
    // ================= far path =================
    const int idx2 = bid - 512;
    const int b = idx2 >> 7;     // 0..7
    const int seg = idx2 & 127;  // 0..127 -> t in [seg*256, seg*256+256)
    float* Cf   = (float*)SMEM;          // [2][16] coeffs
    int*   scnt = (int*)(Cf + 32);       // [2]
    int*   slst = scnt + 2;              // [2][64]

    const int w = tid >> 6;              // wave 0..3
    const int e = tid & 63;
    if (w < 2) {
      const int tile = 2 * seg + w;
      const int be = b * 64 + e;
      const float4 A  = params[be * 3 + 0];
      const float4 B4 = params[be * 3 + 1];
      const float4 C4 = params[be * 3 + 2];
      const float4 D4 = mom2[be];
      const float M[13] = {A.w, B4.x, B4.y, B4.z, B4.w,
                           C4.x, C4.y, C4.z, C4.w, D4.x, D4.y, D4.z, D4.w};

      const float ts = (float)(tile * 128);
      const float te = ts + 128.f;
      const float lo = A.y, hi = A.z;
      const bool inter   = (lo < te) && (hi > ts);
      const bool inside  = (lo <= ts) && (te <= hi);
      const bool special = inter && !inside;

      float Bj[13];
#pragma unroll
      for (int j = 0; j < 13; ++j) Bj[j] = 0.f;

      if (!inter) {
        const float th = (ts + 63.5f - A.x) * KTH;
        const float sn = __sinf(th), cs = __cosf(th);
        const float c = cs * __builtin_amdgcn_rcpf(sn);
        float a[13];
        a[0] = c; a[1] = -__builtin_fmaf(c, c, 1.f);
        float s;
        s = 2.f * a[0] * a[1];                                      a[2]  = -0.5f * s;
        s = __builtin_fmaf(2.f * a[0], a[2], a[1] * a[1]);          a[3]  = (-1.f / 3.f) * s;
        s = 2.f * (a[0] * a[3] + a[1] * a[2]);                      a[4]  = -0.25f * s;
        s = __builtin_fmaf(2.f, a[0] * a[4] + a[1] * a[3], a[2] * a[2]); a[5] = -0.2f * s;
        s = 2.f * (a[0] * a[5] + a[1] * a[4] + a[2] * a[3]);        a[6]  = (-1.f / 6.f) * s;
        s = __builtin_fmaf(2.f, a[0] * a[6] + a[1] * a[5] + a[2] * a[4], a[3] * a[3]); a[7] = (-1.f / 7.f) * s;
        s = 2.f * (a[0] * a[7] + a[1] * a[6] + a[2] * a[5] + a[3] * a[4]); a[8] = -0.125f * s;
        s = __builtin_fmaf(2.f, a[0] * a[8] + a[1] * a[7] + a[2] * a[6] + a[3] * a[5], a[4] * a[4]); a[9] = (-1.f / 9.f) * s;
        s = 2.f * (a[0] * a[9] + a[1] * a[8] + a[2] * a[7] + a[3] * a[6] + a[4] * a[5]); a[10] = -0.1f * s;
        s = __builtin_fmaf(2.f, a[0] * a[10] + a[1] * a[9] + a[2] * a[8] + a[3] * a[7] + a[4] * a[6], a[5] * a[5]); a[11] = (-1.f / 11.f) * s;
        s = 2.f * (a[0] * a[11] + a[1] * a[10] + a[2] * a[9] + a[3] * a[8] + a[4] * a[7] + a[5] * a[6]); a[12] = (-1.f / 12.f) * s;

        const float BIN[13][13] = {
          {1,0,0,0,0,0,0,0,0,0,0,0,0},
          {1,1,0,0,0,0,0,0,0,0,0,0,0},
          {1,2,1,0,0,0,0,0,0,0,0,0,0},
          {1,3,3,1,0,0,0,0,0,0,0,0,0},
          {1,4,6,4,1,0,0,0,0,0,0,0,0},
          {1,5,10,10,5,1,0,0,0,0,0,0,0},
          {1,6,15,20,15,6,1,0,0,0,0,0,0},
          {1,7,21,35,35,21,7,1,0,0,0,0,0},
          {1,8,28,56,70,56,28,8,1,0,0,0,0},
          {1,9,36,84,126,126,84,36,9,1,0,0,0},
          {1,10,45,120,210,252,210,120,45,10,1,0,0},
          {1,11,55,165,330,462,462,330,165,55,11,1,0},
          {1,12,66,220,495,792,924,792,495,220,66,12,1}};
#pragma unroll
        for (int j = 0; j < 13; ++j) {
          float acc = 0.f;
#pragma unroll
          for (int m = j; m < 13; ++m)
            acc = __builtin_fmaf(BIN[m][j] * a[m], M[m - j], acc);
          Bj[j] = acc;
        }
      }

#pragma unroll
      for (int j = 0; j < 13; ++j) {
#pragma unroll
        for (int off = 32; off > 0; off >>= 1)
          Bj[j] += __shfl_xor(Bj[j], off);
      }
      if (e == 0) {
#pragma unroll
        for (int j = 0; j < 13; ++j) Cf[w * 16 + j] = Bj[j];
      }
      unsigned long long msk = __ballot(special);
      if (special) {
        int pos = __popcll(msk & ((1ull << e) - 1ull));
        slst[w * 64 + pos] = be;
      }
      if (e == 0) scnt[w] = (int)__popcll(msk);
    }
    __syncthreads();

    const int t = seg * 256 + tid;
    const int tw = tid >> 7;             // which of this block's 2 tiles
    const float* cc = Cf + tw * 16;      // wave-uniform LDS base (broadcast)
    const float tf = (float)t;
    const float h = (tf - ((float)((2 * seg + tw) * 128) + 63.5f)) * KTH;
    float y = cc[12];
    y = __builtin_fmaf(y, h, cc[11]);
    y = __builtin_fmaf(y, h, cc[10]);
    y = __builtin_fmaf(y, h, cc[9]);
    y = __builtin_fmaf(y, h, cc[8]);
    y = __builtin_fmaf(y, h, cc[7]);
    y = __builtin_fmaf(y, h, cc[6]);
    y = __builtin_fmaf(y, h, cc[5]);
    y = __builtin_fmaf(y, h, cc[4]);
    y = __builtin_fmaf(y, h, cc[3]);
    y = __builtin_fmaf(y, h, cc[2]);
    y = __builtin_fmaf(y, h, cc[1]);
    y = __builtin_fmaf(y, h, cc[0]);

    const int cnt = scnt[tw];            // wave-uniform
    for (int i = 0; i < cnt; ++i) {
      const int se = slst[tw * 64 + i];
      const float4 A  = params[se * 3 + 0];
      const float4 B4 = params[se * 3 + 1];
      const float4 C4 = params[se * 3 + 2];
      y += p8_far(tf, A, B4, C4);
    }
    atomicAdd(&out[b * NS + t], (t & 1) ? -y : y);
    return;
  }

  // ================= near conv =================
  const int be = bid;
  const int m0 = m0s[be];
  const int start = m0 - W1;
  if (start >= NS) return;       // window past output range
  const float fr = fracs[be];
  const int b = be >> 6;

  float4* Tsplit = SMEM;         // [0..319]=even groups, [320..639]=odd
  float*  Tf = (float*)Tsplit;
  float*  Gl = (float*)(SMEM + 640);
  const float4* Gl4 = SMEM + 640;

  for (int i = tid; i < AS; i += 256) Gl[i] = G[be * AS + i];
  for (int i = tid; i < 2560; i += 256) {
    int v = start - 511 + i;
    float w = (float)(v - m0) - fr;           // never 0 (|fr| >= 1e-9)
    float th = w * KTH;                       // |th| <= 0.041
    float q = th * th;
    float sn = th * __builtin_fmaf(q, __builtin_fmaf(q, (1.f / 120.f), (-1.f / 6.f)), 1.f);
    float cs = __builtin_fmaf(q, __builtin_fmaf(q, (1.f / 24.f), -0.5f), 1.f);
    float val = cs * __builtin_amdgcn_rcpf(sn);
    int g = i >> 2;                           // logical float4 group
    int s = (g >> 1) * 4 + (i & 3) + (g & 1) * 1280;  // split index (floats)
    Tf[s] = val;
  }
  __syncthreads();

  float acc[8];
#pragma unroll
  for (int r = 0; r < 8; ++r) acc[r] = 0.f;

  float Wf[16];
  {
    float4 qa = Tsplit[tid];         // group 2*tid   -> Wf[0..3]
    float4 qb = Tsplit[320 + tid];   // group 2*tid+1 -> Wf[4..7]
    Wf[0] = qa.x; Wf[1] = qa.y; Wf[2] = qa.z; Wf[3] = qa.w;
    Wf[4] = qb.x; Wf[5] = qb.y; Wf[6] = qb.z; Wf[7] = qb.w;
  }
#pragma unroll 4
  for (int k = 0; k < 64; ++k) {
    float4 qa = Tsplit[tid + k + 1];         // group 2(tid+k+1)
    float4 qb = Tsplit[320 + tid + k + 1];   // group 2(tid+k+1)+1
    Wf[8]  = qa.x; Wf[9]  = qa.y; Wf[10] = qa.z; Wf[11] = qa.w;
    Wf[12] = qb.x; Wf[13] = qb.y; Wf[14] = qb.z; Wf[15] = qb.w;
    const int tc = 504 - 8 * k;
    const float4 gq0 = Gl4[tc >> 2];
    const float4 gq1 = Gl4[(tc >> 2) + 1];
    const float gvals[8] = {gq0.x, gq0.y, gq0.z, gq0.w,
                            gq1.x, gq1.y, gq1.z, gq1.w};
#pragma unroll
    for (int d = 0; d < 8; ++d) {
      const float gv = gvals[d];
#pragma unroll
      for (int r = 0; r < 8; ++r)
        acc[r] = fmaf(gv, Wf[7 + r - d], acc[r]);
    }
#pragma unroll
    for (int m = 0; m < 8; ++m) Wf[m] = Wf[m + 8];
  }

  const int tb = start + tid * 8;
#pragma unroll
  for (int r = 0; r < 8; ++r) {
    int t = tb + r;
    if (t >= 0 && t < NS) {
      float v = (t & 1) ? -acc[r] : acc[r];
      atomicAdd(&out[b * NS + t], v);
    }
  }
}

// ---------------------------------------------------------------------------
extern "C" void kernel_launch(void* const* d_in, const int* in_sizes, int n_in,
                              void* d_out, int out_size, void* d_ws, size_t ws_size,
                              hipStream_t stream) {
  const float* x     = (const float*)d_in[0];
  const float* times = (const float*)d_in[1];
  const float* gu    = (const float*)d_in[2];
  const float* atoms = (const float*)d_in[3];
  const float* tw0 = (const float*)d_in[4];  const float* tb0 = (const float*)d_in[5];
  const float* tw1 = (const float*)d_in[6];  const float* tb1 = (const float*)d_in[7];
  const float* tw2 = (const float*)d_in[8];  const float* tb2 = (const float*)d_in[9];
  const float* sw0 = (const float*)d_in[10]; const float* sb0 = (const float*)d_in[11];
  const float* sw1 = (const float*)d_in[12]; const float* sb1 = (const float*)d_in[13];
  const float* sw2 = (const float*)d_in[14]; const float* sb2 = (const float*)d_in[15];
  const float* aw0 = (const float*)d_in[16]; const float* ab0 = (const float*)d_in[17];
  const float* aw1 = (const float*)d_in[18]; const float* ab1 = (const float*)d_in[19];
  const float* aw2 = (const float*)d_in[20]; const float* ab2 = (const float*)d_in[21];

  // ws layout (bytes):
  //   G       0        (1048576)
  //   m0s     1048576  (2048)
  //   fracs   1050624  (2048)
  //   params  1052672  (24576)
  //   timev   1077248  (2048)
  //   ampv    1079296  (2048)
  //   mom2    1081344  (8192)
  //   partials 1089536 (65536)
  char* wsb = (char*)d_ws;
  float*  G        = (float*)wsb;
  int*    m0s      = (int*)(wsb + 1048576);
  float*  fracs    = (float*)(wsb + 1050624);
  float4* params   = (float4*)(wsb + 1052672);
  float*  timev    = (float*)(wsb + 1077248);
  float*  ampv     = (float*)(wsb + 1079296);
  float4* mom2     = (float4*)(wsb + 1081344);
  float2* partials = (float2*)(wsb + 1089536);

  prepA_kernel<<<2304, 128, 0, stream>>>(
      x, times, gu, tw0, tb0, tw1, tb1, tw2, tb2,
      sw0, sb0, sw1, sb1, sw2, sb2,
      aw0, ab0, aw1, ab1, aw2, ab2,
      timev, ampv, partials, (float*)d_out);

  finalize_kernel<<<NBE, 128, 0, stream>>>(partials, timev, ampv, atoms,
                                           G, m0s, fracs, params, mom2);

  field_kernel<<<1536, 256, 0, stream>>>(params, mom2, G, m0s, fracs,
                                         (float*)d_out);
}

// Round 13
// 67.015 us; speedup vs baseline: 1.0834x; 1.0834x over previous
//
#include <hip/hip_runtime.h>
#include <math.h>

#define MD 128
#define NA 2048
#define AS 512
#define NS 32768
#define NBE 512
#define W1 768
#define W2 1280
#define PI 3.14159265358979323846
#define KTH ((float)(PI / 98304.0))

__device__ __forceinline__ float lrelu(float v) { return v > 0.f ? v : 0.2f * v; }

// ---------------------------------------------------------------------------
// P8 far evaluation for one (t, e): Taylor of cot around atom center, masked
// to 0 inside the near window. (Round-8-proven formula.)
// ---------------------------------------------------------------------------
__device__ __forceinline__ float p8_far(float tf, float4 A, float4 B, float4 C)
{
  float u  = tf - A.x;
  float th = u * KTH;
  float sn = __sinf(th);
  float cs = __cosf(th);
  float c  = cs * __builtin_amdgcn_rcpf(sn);
  float u2  = __builtin_fmaf(c, c, 1.f);     // -a1
  float c2  = c + c;
  float u22 = u2 + u2;
  float a2  = c * u2;
  float a3  = (-1.f / 3.f) * __builtin_fmaf(c2, a2, u2 * u2);
  float a4  = 0.5f * __builtin_fmaf(-c, a3, u2 * a2);
  float s5  = __builtin_fmaf(c2, a4, a2 * a2);
  s5        = __builtin_fmaf(-u22, a3, s5);
  float a5  = -0.2f * s5;
  float s6  = __builtin_fmaf(c, a5, a2 * a3);
  s6        = __builtin_fmaf(-u2, a4, s6);
  float a6  = (-1.f / 3.f) * s6;
  float s7  = __builtin_fmaf(c2, a6, a3 * a3);
  s7        = __builtin_fmaf(-u22, a5, s7);
  s7        = __builtin_fmaf(2.f * a2, a4, s7);
  float a7  = (-1.f / 7.f) * s7;
  float s8  = __builtin_fmaf(c, a7, a3 * a4);
  s8        = __builtin_fmaf(-u2, a6, s8);
  s8        = __builtin_fmaf(a2, a5, s8);
  float a8  = -0.25f * s8;
  float y = c * A.w;
  y = __builtin_fmaf(-u2, B.x, y);
  y = __builtin_fmaf(a2, B.y, y);
  y = __builtin_fmaf(a3, B.z, y);
  y = __builtin_fmaf(a4, B.w, y);
  y = __builtin_fmaf(a5, C.x, y);
  y = __builtin_fmaf(a6, C.y, y);
  y = __builtin_fmaf(a7, C.z, y);
  y = __builtin_fmaf(a8, C.w, y);
  bool farq = (tf < A.y) || (tf >= A.z);
  return farq ? y : 0.f;
}

// ---------------------------------------------------------------------------
// P1: hidden layers for all 3 stacks + d_out zeroing.
// Round-13 change: 2 rows per block (was 4) -> grid (256, 3) = 1536 waves
// (1.5/SIMD, was 0.75) for latency hiding. Weight loads stay coalesced/L2-hot.
// ---------------------------------------------------------------------------
__global__ __launch_bounds__(128) void hidden_kernel(
    const float* __restrict__ x, const float* __restrict__ times,
    const float* __restrict__ tw0, const float* __restrict__ tb0,
    const float* __restrict__ tw1, const float* __restrict__ tb1,
    const float* __restrict__ tw2, const float* __restrict__ tb2,
    const float* __restrict__ sw0, const float* __restrict__ sb0,
    const float* __restrict__ sw1, const float* __restrict__ sb1,
    const float* __restrict__ aw0, const float* __restrict__ ab0,
    const float* __restrict__ aw1, const float* __restrict__ ab1,
    const float* __restrict__ aw2, const float* __restrict__ ab2,
    float* __restrict__ timev, float* __restrict__ ampv,
    float* __restrict__ h2sel, float* __restrict__ out)
{
  const int rg = blockIdx.x;      // 0..255 (2 rows each)
  const int stack = blockIdx.y;   // 0=time 1=amp 2=sel
  const int tid = threadIdx.x;

  // ---- zero d_out (replaces hipMemsetAsync dispatch) ----
  {
    const int gtid = (stack * 256 + rg) * 128 + tid;   // 0..98303
    if (gtid < (8 * NS) / 4)
      ((float4*)out)[gtid] = make_float4(0.f, 0.f, 0.f, 0.f);
  }

  __shared__ float xs[2][MD];
  __shared__ double dA[2][MD], dB[2][MD];
  __shared__ float fA[2][MD], fB[2][MD];

#pragma unroll
  for (int j = 0; j < 2; ++j) xs[j][tid] = x[(rg * 2 + j) * MD + tid];
  __syncthreads();

  if (stack == 0) {
    // ---- time stack, fp64 (dNc = 32767*dtime: precision-critical) ----
    {
      double b = (double)tb0[tid];
      double s[2] = {b, b};
#pragma unroll 8
      for (int k = 0; k < MD; ++k) {
        double w = (double)tw0[k * MD + tid];
#pragma unroll
        for (int j = 0; j < 2; ++j) s[j] += (double)xs[j][k] * w;
      }
#pragma unroll
      for (int j = 0; j < 2; ++j) dA[j][tid] = s[j] > 0.0 ? s[j] : 0.2 * s[j];
      __syncthreads();
    }
    {
      double b = (double)tb1[tid];
      double s[2] = {b, b};
#pragma unroll 8
      for (int k = 0; k < MD; ++k) {
        double w = (double)tw1[k * MD + tid];
#pragma unroll
        for (int j = 0; j < 2; ++j) s[j] += dA[j][k] * w;
      }
#pragma unroll
      for (int j = 0; j < 2; ++j) dB[j][tid] = s[j] > 0.0 ? s[j] : 0.2 * s[j];
      __syncthreads();
    }
    {
      double w2 = (double)tw2[tid];
#pragma unroll
      for (int j = 0; j < 2; ++j) dA[j][tid] = dB[j][tid] * w2;
      __syncthreads();
      for (int off = 64; off > 0; off >>= 1) {
        if (tid < off) {
#pragma unroll
          for (int j = 0; j < 2; ++j) dA[j][tid] += dA[j][tid + off];
        }
        __syncthreads();
      }
      if (tid == 0) {
#pragma unroll
        for (int j = 0; j < 2; ++j) {
          double tval = dA[j][0] + (double)tb2[0];
          double sg = 1.0 / (1.0 + exp(-tval));
          float tf = (float)sg;            // round like the fp32 reference
          timev[rg * 2 + j] = tf * 1.0f + times[rg * 2 + j];
        }
      }
    }
  } else if (stack == 1) {
    // ---- amp stack, fp32 ----
    {
      float b = ab0[tid];
      float s[2] = {b, b};
#pragma unroll 8
      for (int k = 0; k < MD; ++k) {
        float w = aw0[k * MD + tid];
#pragma unroll
        for (int j = 0; j < 2; ++j) s[j] += xs[j][k] * w;
      }
#pragma unroll
      for (int j = 0; j < 2; ++j) fA[j][tid] = lrelu(s[j]);
      __syncthreads();
    }
    {
      float b = ab1[tid];
      float s[2] = {b, b};
#pragma unroll 8
      for (int k = 0; k < MD; ++k) {
        float w = aw1[k * MD + tid];
#pragma unroll
        for (int j = 0; j < 2; ++j) s[j] += fA[j][k] * w;
      }
#pragma unroll
      for (int j = 0; j < 2; ++j) fB[j][tid] = lrelu(s[j]);
      __syncthreads();
    }
    {
      float w2 = aw2[tid];
#pragma unroll
      for (int j = 0; j < 2; ++j) fA[j][tid] = fB[j][tid] * w2;
      __syncthreads();
      for (int off = 64; off > 0; off >>= 1) {
        if (tid < off) {
#pragma unroll
          for (int j = 0; j < 2; ++j) fA[j][tid] += fA[j][tid + off];
        }
        __syncthreads();
      }
      if (tid == 0) {
#pragma unroll
        for (int j = 0; j < 2; ++j) {
          float av = fA[j][0] + ab2[0];
          ampv[rg * 2 + j] = av * av;
        }
      }
    }
  } else {
    // ---- selection hidden, fp32 ----
    {
      float b = sb0[tid];
      float s[2] = {b, b};
#pragma unroll 8
      for (int k = 0; k < MD; ++k) {
        float w = sw0[k * MD + tid];
#pragma unroll
        for (int j = 0; j < 2; ++j) s[j] += xs[j][k] * w;
      }
#pragma unroll
      for (int j = 0; j < 2; ++j) fA[j][tid] = lrelu(s[j]);
      __syncthreads();
    }
    {
      float b = sb1[tid];
      float s[2] = {b, b};
#pragma unroll 8
      for (int k = 0; k < MD; ++k) {
        float w = sw1[k * MD + tid];
#pragma unroll
        for (int j = 0; j < 2; ++j) s[j] += fA[j][k] * w;
      }
#pragma unroll
      for (int j = 0; j < 2; ++j)
        h2sel[(rg * 2 + j) * MD + tid] = lrelu(s[j]);
    }
  }
}

// ---------------------------------------------------------------------------
// P2 (round-5 proven shape): selection logits + gumbel + argmax partials.
// Round-13 change: __logf (HW v_log_f32) for the gumbel double-log —
// g error ~1e-6, argmax gaps O(1) -> no flips; removes ~8.4M libm calls.
// Grid (16 o-tiles, 128 be-groups) x 128.
// ---------------------------------------------------------------------------
__global__ __launch_bounds__(128) void logits_kernel(
    const float* __restrict__ h2sel, const float* __restrict__ gu,
    const float* __restrict__ sw2, const float* __restrict__ sb2,
    float2* __restrict__ partials)
{
  const int ot = blockIdx.x;     // 0..15
  const int beg = blockIdx.y;    // 0..127
  const int tid = threadIdx.x;
  const int o = ot * 128 + tid;
  const int wave = tid >> 6, lane = tid & 63;

  __shared__ float h2s[4][MD];
  __shared__ float wv[2][4];
  __shared__ int wi[2][4];

#pragma unroll
  for (int j = 0; j < 4; ++j) h2s[j][tid] = h2sel[(beg * 4 + j) * MD + tid];
  __syncthreads();

  float b = sb2[o];
  float acc[4] = {b, b, b, b};
#pragma unroll 16
  for (int k = 0; k < MD; ++k) {
    float w = sw2[k * NA + o];
#pragma unroll
    for (int j = 0; j < 4; ++j) acc[j] = fmaf(h2s[j][k], w, acc[j]);
  }

#pragma unroll
  for (int j = 0; j < 4; ++j) {
    float u = gu[(beg * 4 + j) * NA + o];
    float g = -__logf(-__logf(u + 1e-10f) + 1e-10f);
    float v = acc[j] + g;
    int idx = o;
    for (int off = 32; off > 0; off >>= 1) {
      float ov = __shfl_xor(v, off);
      int oi = __shfl_xor(idx, off);
      if (ov > v || (ov == v && oi < idx)) { v = ov; idx = oi; }
    }
    if (lane == 0) { wv[wave][j] = v; wi[wave][j] = idx; }
  }
  __syncthreads();
  if (tid == 0) {
#pragma unroll
    for (int j = 0; j < 4; ++j) {
      float v0 = wv[0][j], v1 = wv[1][j];
      int i0 = wi[0][j], i1 = wi[1][j];
      bool take1 = (v1 > v0) || (v1 == v0 && i1 < i0);
      float bv = take1 ? v1 : v0;
      int bi = take1 ? i1 : i0;
      partials[(beg * 4 + j) * 16 + ot] = make_float2(bv, __int_as_float(bi));
    }
  }
}

// ---------------------------------------------------------------------------
// finalize (round-11 proven): partials argmax + atom norm + shift params +
// G + moments M0..M12, atom row as one float4 read.
// ---------------------------------------------------------------------------
__global__ __launch_bounds__(128) void finalize_kernel(
    const float2* __restrict__ partials, const float* __restrict__ timev,
    const float* __restrict__ ampv, const float* __restrict__ atoms,
    float* __restrict__ G, int* __restrict__ m0s, float* __restrict__ fracs,
    float4* __restrict__ params, float4* __restrict__ mom2)
{
  const int be = blockIdx.x;
  const int tid = threadIdx.x;
  __shared__ float red[128];
  __shared__ float m_red[128][13];
  __shared__ float sc_coef, sc_inv;
  __shared__ int sc_idx;

  if (tid < 64) {
    float v = -3.4e38f;
    int idx = 0x7fffffff;
    if (tid < 16) {
      float2 p = partials[be * 16 + tid];
      v = p.x;
      idx = __float_as_int(p.y);
    }
    for (int off = 8; off > 0; off >>= 1) {
      float ov = __shfl_xor(v, off);
      int oi = __shfl_xor(idx, off);
      if (ov > v || (ov == v && oi < idx)) { v = ov; idx = oi; }
    }
    if (tid == 0) sc_idx = idx;
  }
  __syncthreads();
  const int idx = sc_idx;

  const float4 a4 = ((const float4*)(atoms + (size_t)idx * AS))[tid];

  {
    float ss = a4.x * a4.x + a4.y * a4.y + a4.z * a4.z + a4.w * a4.w;
    red[tid] = ss;
    __syncthreads();
    for (int off = 64; off > 0; off >>= 1) {
      if (tid < off) red[tid] += red[tid + off];
      __syncthreads();
    }
    if (tid == 0) {
      sc_inv = 1.f / (sqrtf(red[0]) + 1e-8f);
      double Nc = (double)timev[be] * (1610612736.0 / 49153.0);
      double rr = rint(Nc);
      int m0 = (int)rr;
      float fr = (float)(Nc - rr);
      if (fabsf(fr) < 1e-9f) fr = (fr < 0.f) ? -1e-9f : 1e-9f;
      m0s[be] = m0;
      fracs[be] = fr;
      sc_coef = ampv[be] * ((m0 & 1) ? 1.0f : -1.0f) *
                sinf((float)PI * fr) * (1.0f / 98304.0f);
      red[64] = (float)m0;
      red[65] = fr;
    }
    __syncthreads();
  }

  const float cf = sc_coef * sc_inv;
  float mk[13];
#pragma unroll
  for (int k = 0; k < 13; ++k) mk[k] = 0.f;
  const float av4[4] = {a4.x * cf, a4.y * cf, a4.z * cf, a4.w * cf};
  float4 gv4;
  float* gvp = (float*)&gv4;
  const int t0 = tid * 4;
#pragma unroll
  for (int j = 0; j < 4; ++j) {
    const int t = t0 + j;
    float gv = (j & 1) ? -av4[j] : av4[j];   // t0 even -> parity = j parity
    gvp[j] = gv;
    float q = (255.5f - (float)t) * KTH;     // -(tau-255.5)*pi/N
    float pw = gv;
    mk[0] += pw;
#pragma unroll
    for (int k = 1; k < 13; ++k) { pw *= q; mk[k] += pw; }
  }
  ((float4*)(G + (size_t)be * AS))[tid] = gv4;
#pragma unroll
  for (int k = 0; k < 13; ++k) m_red[tid][k] = mk[k];
  __syncthreads();
  for (int off = 64; off > 0; off >>= 1) {
    if (tid < off) {
#pragma unroll
      for (int k = 0; k < 13; ++k) m_red[tid][k] += m_red[tid + off][k];
    }
    __syncthreads();
  }
  if (tid == 0) {
    int m0 = (int)red[64];
    float fr = red[65];
    float uc = (float)((double)m0 + (double)fr + 255.5);
    params[be * 3 + 0] = make_float4(uc, (float)(m0 - W1), (float)(m0 + W2), m_red[0][0]);
    params[be * 3 + 1] = make_float4(m_red[0][1], m_red[0][2], m_red[0][3], m_red[0][4]);
    params[be * 3 + 2] = make_float4(m_red[0][5], m_red[0][6], m_red[0][7], m_red[0][8]);
    mom2[be] = make_float4(m_red[0][9], m_red[0][10], m_red[0][11], m_red[0][12]);
  }
}

// ---------------------------------------------------------------------------
// field (round-11 proven): blocks [0,512) = near conv (split-table);
// blocks [512,1536) = far: inline per-tile coeff collapse then Horner.
// ---------------------------------------------------------------------------
__global__ __launch_bounds__(256) void field_kernel(
    const float4* __restrict__ params, const float4* __restrict__ mom2,
    const float* __restrict__ G, const int* __restrict__ m0s,
    const float* __restrict__ fracs, float* __restrict__ out)
{
  __shared__ float4 SMEM[768];   // near: Tsplit[640]+Gl4[128] | far: coeff area
  const int bid = blockIdx.x;
  const int tid = threadIdx.x;

  if (bid >= 512) {
    // ================= far path =================
    const int idx2 = bid - 512;
    const int b = idx2 >> 7;     // 0..7
    const int seg = idx2 & 127;  // 0..127 -> t in [seg*256, seg*256+256)
    float* Cf   = (float*)SMEM;          // [2][16] coeffs
    int*   scnt = (int*)(Cf + 32);       // [2]
    int*   slst = scnt + 2;              // [2][64]

    const int w = tid >> 6;              // wave 0..3
    const int e = tid & 63;
    if (w < 2) {
      const int tile = 2 * seg + w;
      const int be = b * 64 + e;
      const float4 A  = params[be * 3 + 0];
      const float4 B4 = params[be * 3 + 1];
      const float4 C4 = params[be * 3 + 2];
      const float4 D4 = mom2[be];
      const float M[13] = {A.w, B4.x, B4.y, B4.z, B4.w,
                           C4.x, C4.y, C4.z, C4.w, D4.x, D4.y, D4.z, D4.w};

      const float ts = (float)(tile * 128);
      const float te = ts + 128.f;
      const float lo = A.y, hi = A.z;
      const bool inter   = (lo < te) && (hi > ts);
      const bool inside  = (lo <= ts) && (te <= hi);
      const bool special = inter && !inside;

      float Bj[13];
#pragma unroll
      for (int j = 0; j < 13; ++j) Bj[j] = 0.f;

      if (!inter) {
        const float th = (ts + 63.5f - A.x) * KTH;
        const float sn = __sinf(th), cs = __cosf(th);
        const float c = cs * __builtin_amdgcn_rcpf(sn);
        float a[13];
        a[0] = c; a[1] = -__builtin_fmaf(c, c, 1.f);
        float s;
        s = 2.f * a[0] * a[1];                                      a[2]  = -0.5f * s;
        s = __builtin_fmaf(2.f * a[0], a[2], a[1] * a[1]);          a[3]  = (-1.f / 3.f) * s;
        s = 2.f * (a[0] * a[3] + a[1] * a[2]);                      a[4]  = -0.25f * s;
        s = __builtin_fmaf(2.f, a[0] * a[4] + a[1] * a[3], a[2] * a[2]); a[5] = -0.2f * s;
        s = 2.f * (a[0] * a[5] + a[1] * a[4] + a[2] * a[3]);        a[6]  = (-1.f / 6.f) * s;
        s = __builtin_fmaf(2.f, a[0] * a[6] + a[1] * a[5] + a[2] * a[4], a[3] * a[3]); a[7] = (-1.f / 7.f) * s;
        s = 2.f * (a[0] * a[7] + a[1] * a[6] + a[2] * a[5] + a[3] * a[4]); a[8] = -0.125f * s;
        s = __builtin_fmaf(2.f, a[0] * a[8] + a[1] * a[7] + a[2] * a[6] + a[3] * a[5], a[4] * a[4]); a[9] = (-1.f / 9.f) * s;
        s = 2.f * (a[0] * a[9] + a[1] * a[8] + a[2] * a[7] + a[3] * a[6] + a[4] * a[5]); a[10] = -0.1f * s;
        s = __builtin_fmaf(2.f, a[0] * a[10] + a[1] * a[9] + a[2] * a[8] + a[3] * a[7] + a[4] * a[6], a[5] * a[5]); a[11] = (-1.f / 11.f) * s;
        s = 2.f * (a[0] * a[11] + a[1] * a[10] + a[2] * a[9] + a[3] * a[8] + a[4] * a[7] + a[5] * a[6]); a[12] = (-1.f / 12.f) * s;

        const float BIN[13][13] = {
          {1,0,0,0,0,0,0,0,0,0,0,0,0},
          {1,1,0,0,0,0,0,0,0,0,0,0,0},
          {1,2,1,0,0,0,0,0,0,0,0,0,0},
          {1,3,3,1,0,0,0,0,0,0,0,0,0},
          {1,4,6,4,1,0,0,0,0,0,0,0,0},
          {1,5,10,10,5,1,0,0,0,0,0,0,0},
          {1,6,15,20,15,6,1,0,0,0,0,0,0},
          {1,7,21,35,35,21,7,1,0,0,0,0,0},
          {1,8,28,56,70,56,28,8,1,0,0,0,0},
          {1,9,36,84,126,126,84,36,9,1,0,0,0},
          {1,10,45,120,210,252,210,120,45,10,1,0,0},
          {1,11,55,165,330,462,462,330,165,55,11,1,0},
          {1,12,66,220,495,792,924,792,495,220,66,12,1}};
#pragma unroll
        for (int j = 0; j < 13; ++j) {
          float acc = 0.f;
#pragma unroll
          for (int m = j; m < 13; ++m)
            acc = __builtin_fmaf(BIN[m][j] * a[m], M[m - j], acc);
          Bj[j] = acc;
        }
      }

#pragma unroll
      for (int j = 0; j < 13; ++j) {
#pragma unroll
        for (int off = 32; off > 0; off >>= 1)
          Bj[j] += __shfl_xor(Bj[j], off);
      }
      if (e == 0) {
#pragma unroll
        for (int j = 0; j < 13; ++j) Cf[w * 16 + j] = Bj[j];
      }
      unsigned long long msk = __ballot(special);
      if (special) {
        int pos = __popcll(msk & ((1ull << e) - 1ull));
        slst[w * 64 + pos] = be;
      }
      if (e == 0) scnt[w] = (int)__popcll(msk);
    }
    __syncthreads();

    const int t = seg * 256 + tid;
    const int tw = tid >> 7;             // which of this block's 2 tiles
    const float* cc = Cf + tw * 16;      // wave-uniform LDS base (broadcast)
    const float tf = (float)t;
    const float h = (tf - ((float)((2 * seg + tw) * 128) + 63.5f)) * KTH;
    float y = cc[12];
    y = __builtin_fmaf(y, h, cc[11]);
    y = __builtin_fmaf(y, h, cc[10]);
    y = __builtin_fmaf(y, h, cc[9]);
    y = __builtin_fmaf(y, h, cc[8]);
    y = __builtin_fmaf(y, h, cc[7]);
    y = __builtin_fmaf(y, h, cc[6]);
    y = __builtin_fmaf(y, h, cc[5]);
    y = __builtin_fmaf(y, h, cc[4]);
    y = __builtin_fmaf(y, h, cc[3]);
    y = __builtin_fmaf(y, h, cc[2]);
    y = __builtin_fmaf(y, h, cc[1]);
    y = __builtin_fmaf(y, h, cc[0]);

    const int cnt = scnt[tw];            // wave-uniform
    for (int i = 0; i < cnt; ++i) {
      const int se = slst[tw * 64 + i];
      const float4 A  = params[se * 3 + 0];
      const float4 B4 = params[se * 3 + 1];
      const float4 C4 = params[se * 3 + 2];
      y += p8_far(tf, A, B4, C4);
    }
    atomicAdd(&out[b * NS + t], (t & 1) ? -y : y);
    return;
  }

  // ================= near conv =================
  const int be = bid;
  const int m0 = m0s[be];
  const int start = m0 - W1;
  if (start >= NS) return;       // window past output range
  const float fr = fracs[be];
  const int b = be >> 6;

  float4* Tsplit = SMEM;         // [0..319]=even groups, [320..639]=odd
  float*  Tf = (float*)Tsplit;
  float*  Gl = (float*)(SMEM + 640);
  const float4* Gl4 = SMEM + 640;

  for (int i = tid; i < AS; i += 256) Gl[i] = G[be * AS + i];
  for (int i = tid; i < 2560; i += 256) {
    int v = start - 511 + i;
    float w = (float)(v - m0) - fr;           // never 0 (|fr| >= 1e-9)
    float th = w * KTH;                       // |th| <= 0.041
    float q = th * th;
    float sn = th * __builtin_fmaf(q, __builtin_fmaf(q, (1.f / 120.f), (-1.f / 6.f)), 1.f);
    float cs = __builtin_fmaf(q, __builtin_fmaf(q, (1.f / 24.f), -0.5f), 1.f);
    float val = cs * __builtin_amdgcn_rcpf(sn);
    int g = i >> 2;                           // logical float4 group
    int s = (g >> 1) * 4 + (i & 3) + (g & 1) * 1280;  // split index (floats)
    Tf[s] = val;
  }
  __syncthreads();

  float acc[8];
#pragma unroll
  for (int r = 0; r < 8; ++r) acc[r] = 0.f;

  float Wf[16];
  {
    float4 qa = Tsplit[tid];         // group 2*tid   -> Wf[0..3]
    float4 qb = Tsplit[320 + tid];   // group 2*tid+1 -> Wf[4..7]
    Wf[0] = qa.x; Wf[1] = qa.y; Wf[2] = qa.z; Wf[3] = qa.w;
    Wf[4] = qb.x; Wf[5] = qb.y; Wf[6] = qb.z; Wf[7] = qb.w;
  }
#pragma unroll 4
  for (int k = 0; k < 64; ++k) {
    float4 qa = Tsplit[tid + k + 1];         // group 2(tid+k+1)
    float4 qb = Tsplit[320 + tid + k + 1];   // group 2(tid+k+1)+1
    Wf[8]  = qa.x; Wf[9]  = qa.y; Wf[10] = qa.z; Wf[11] = qa.w;
    Wf[12] = qb.x; Wf[13] = qb.y; Wf[14] = qb.z; Wf[15] = qb.w;
    const int tc = 504 - 8 * k;
    const float4 gq0 = Gl4[tc >> 2];
    const float4 gq1 = Gl4[(tc >> 2) + 1];
    const float gvals[8] = {gq0.x, gq0.y, gq0.z, gq0.w,
                            gq1.x, gq1.y, gq1.z, gq1.w};
#pragma unroll
    for (int d = 0; d < 8; ++d) {
      const float gv = gvals[d];
#pragma unroll
      for (int r = 0; r < 8; ++r)
        acc[r] = fmaf(gv, Wf[7 + r - d], acc[r]);
    }
#pragma unroll
    for (int m = 0; m < 8; ++m) Wf[m] = Wf[m + 8];
  }

  const int tb = start + tid * 8;
#pragma unroll
  for (int r = 0; r < 8; ++r) {
    int t = tb + r;
    if (t >= 0 && t < NS) {
      float v = (t & 1) ? -acc[r] : acc[r];
      atomicAdd(&out[b * NS + t], v);
    }
  }
}

// ---------------------------------------------------------------------------
extern "C" void kernel_launch(void* const* d_in, const int* in_sizes, int n_in,
                              void* d_out, int out_size, void* d_ws, size_t ws_size,
                              hipStream_t stream) {
  const float* x     = (const float*)d_in[0];
  const float* times = (const float*)d_in[1];
  const float* gu    = (const float*)d_in[2];
  const float* atoms = (const float*)d_in[3];
  const float* tw0 = (const float*)d_in[4];  const float* tb0 = (const float*)d_in[5];
  const float* tw1 = (const float*)d_in[6];  const float* tb1 = (const float*)d_in[7];
  const float* tw2 = (const float*)d_in[8];  const float* tb2 = (const float*)d_in[9];
  const float* sw0 = (const float*)d_in[10]; const float* sb0 = (const float*)d_in[11];
  const float* sw1 = (const float*)d_in[12]; const float* sb1 = (const float*)d_in[13];
  const float* sw2 = (const float*)d_in[14]; const float* sb2 = (const float*)d_in[15];
  const float* aw0 = (const float*)d_in[16]; const float* ab0 = (const float*)d_in[17];
  const float* aw1 = (const float*)d_in[18]; const float* ab1 = (const float*)d_in[19];
  const float* aw2 = (const float*)d_in[20]; const float* ab2 = (const float*)d_in[21];

  // ws layout (bytes):
  //   G       0        (1048576)
  //   m0s     1048576  (2048)
  //   fracs   1050624  (2048)
  //   params  1052672  (24576)
  //   timev   1077248  (2048)
  //   ampv    1079296  (2048)
  //   mom2    1081344  (8192)
  //   h2sel   1089536  (262144)
  //   partials 1351680 (65536)
  char* wsb = (char*)d_ws;
  float*  G        = (float*)wsb;
  int*    m0s      = (int*)(wsb + 1048576);
  float*  fracs    = (float*)(wsb + 1050624);
  float4* params   = (float4*)(wsb + 1052672);
  float*  timev    = (float*)(wsb + 1077248);
  float*  ampv     = (float*)(wsb + 1079296);
  float4* mom2     = (float4*)(wsb + 1081344);
  float*  h2sel    = (float*)(wsb + 1089536);
  float2* partials = (float2*)(wsb + 1351680);

  hidden_kernel<<<dim3(NBE / 2, 3), 128, 0, stream>>>(
      x, times, tw0, tb0, tw1, tb1, tw2, tb2,
      sw0, sb0, sw1, sb1, aw0, ab0, aw1, ab1, aw2, ab2,
      timev, ampv, h2sel, (float*)d_out);

  logits_kernel<<<dim3(16, NBE / 4), 128, 0, stream>>>(h2sel, gu, sw2, sb2, partials);

  finalize_kernel<<<NBE, 128, 0, stream>>>(partials, timev, ampv, atoms,
                                           G, m0s, fracs, params, mom2);

  field_kernel<<<1536, 256, 0, stream>>>(params, mom2, G, m0s, fracs,
                                         (float*)d_out);
}